// Round 4
// baseline (105.125 us; speedup 1.0000x reference)
//
#include <hip/hip_runtime.h>
#include <hip/hip_cooperative_groups.h>
#include <math.h>

namespace cg = cooperative_groups;

#define N 16384
#define LIMIT 8192
#define NT 1024
#define G 16

// key = (float_bits(score) << 14) | index  -- 44-bit unique sort key.
// score = sigmoid(y) in (0,1] => positive float, bits <= 0x3F800000 < 2^30,
// monotone; index < 2^14. (score,index) lex order == jnp stable argsort.
// T = rank-(LIMIT-1) key via distributed radix select; keep iff key <= T.
//
// d_ws layout (poisoned 0xAA each iter -- nothing here relies on zeros
// except gcnt, zeroed by block 0 before grid.sync #1):
//   ws[0]                 : gcnt (candidate ticket counter)
//   ws[16] (byte 64)      : keys[16384] (unsigned long long, 128KB)
//   ws[16+32768]          : ghist[G][1024] block-major (64KB)

template <int W, int WIDTH>
__device__ __forceinline__ void scan_select(unsigned int* tot,
                                            unsigned int* partial,
                                            unsigned long long* prefix_sh,
                                            unsigned int* r_sh) {
    const int tid = threadIdx.x;
    const unsigned int r = *r_sh;          // written before last barrier
    if (tid < 256) {
        unsigned int p = 0;
#pragma unroll
        for (int q = 0; q < W / 4; ++q) {
            uint4 v = ((const uint4*)tot)[tid * (W / 4) + q];
            p += v.x + v.y + v.z + v.w;
        }
        partial[tid] = p;
    }
    __syncthreads();
    if (tid < 64) {                        // wave 0: wave-synchronous
        unsigned int p0 = partial[4*tid+0], p1 = partial[4*tid+1],
                     p2 = partial[4*tid+2], p3 = partial[4*tid+3];
        const unsigned int g4 = p0 + p1 + p2 + p3;
        unsigned int incl = g4;
#pragma unroll
        for (int d = 1; d < 64; d <<= 1) {
            unsigned int up = __shfl_up(incl, d, 64);
            if (tid >= d) incl += up;
        }
        unsigned long long ball = __ballot(incl > r);   // nonzero by rank invariant
        int L = __ffsll((long long)ball) - 1;
        if (tid == L) {
            unsigned int cum = incl - g4;
            unsigned int pp[4] = {p0, p1, p2, p3};
            int grp = -1;
#pragma unroll
            for (int k = 0; k < 4; ++k)
                if (grp < 0) { if (cum + pp[k] > r) grp = 4*L + k; else cum += pp[k]; }
            unsigned int c[W];
#pragma unroll
            for (int q = 0; q < W / 4; ++q) {           // batched, constant-indexed
                uint4 v = ((const uint4*)tot)[grp * (W / 4) + q];
                c[4*q+0] = v.x; c[4*q+1] = v.y; c[4*q+2] = v.z; c[4*q+3] = v.w;
            }
            int b = -1;
#pragma unroll
            for (int k = 0; k < W; ++k)
                if (b < 0) { if (cum + c[k] > r) b = grp * W + k; else cum += c[k]; }
            *r_sh = r - cum;
            *prefix_sh = (*prefix_sh << WIDTH) | (unsigned long long)b;
        }
    }
    __syncthreads();
}

__global__ __launch_bounds__(NT)
void fused_kernel(const float* __restrict__ x, const float* __restrict__ w,
                  float* __restrict__ out, unsigned int* __restrict__ ws) {
    __shared__ __attribute__((aligned(16))) float lds_x[NT + 6];
    __shared__ __attribute__((aligned(16))) unsigned int hist[4096];
    __shared__ __attribute__((aligned(16))) unsigned int partial[256];
    __shared__ unsigned long long prefix_sh;
    __shared__ unsigned int r_sh;

    const int tid = threadIdx.x;
    const int blk = blockIdx.x;
    const int base = blk * NT;
    const int i = base + tid;

    unsigned int* gcnt = ws;
    unsigned long long* keys = (unsigned long long*)(ws + 16);
    unsigned int* ghist = ws + 16 + 2 * 16384;

    if (blk == 0 && tid == 0) *gcnt = 0u;   // before sync #1; atomics are after

    float wv[7];
#pragma unroll
    for (int t = 0; t < 7; ++t) wv[t] = w[t];

    lds_x[3 + tid] = x[i];
    if (tid < 3) {
        int jl = base - 3 + tid;
        lds_x[tid] = (jl >= 0) ? x[jl] : 0.f;
        int jr = base + NT + tid;
        lds_x[NT + 3 + tid] = (jr < N) ? x[jr] : 0.f;
    }
    hist[tid] = 0u;                          // 1024-bin pass-0 histogram
    if (tid == 0) { prefix_sh = 0ULL; r_sh = LIMIT - 1; }
    __syncthreads();

    // conv + sigmoid: bit-exact vs numpy (sequential non-contracted mul/add, expf)
    float acc = 0.f;
#pragma unroll
    for (int t = 0; t < 7; ++t)
        acc = __fadd_rn(acc, __fmul_rn(lds_x[tid + t], wv[t]));
    const float s = 1.f / (1.f + expf(-acc));
    const float xi = lds_x[3 + tid];
    out[N + i] = s;                          // output 1: attention_score

    const unsigned long long key =
        ((unsigned long long)__float_as_uint(s) << 14) | (unsigned int)i;

    // phase 1: private histogram of key bits [43:34], dump to global
    atomicAdd(&hist[(unsigned int)(key >> 34)], 1u);
    __syncthreads();
    ghist[blk * NT + tid] = hist[tid];

    __threadfence();
    cg::this_grid().sync();

    // phase 2 (every block, redundant): reduce G hists, find (b0, r0)
    unsigned int tsum = 0;
#pragma unroll
    for (int b = 0; b < G; ++b) tsum += ghist[b * NT + tid];   // coalesced
    hist[tid] = tsum;
    __syncthreads();
    scan_select<4, 10>(hist, partial, &prefix_sh, &r_sh);
    const unsigned int b0 = (unsigned int)prefix_sh;
    const unsigned int r0 = r_sh;

    // phase 3: compact candidates (bucket == b0) via wave-aggregated ticket
    const bool cand = ((unsigned int)(key >> 34) == b0);
    const unsigned long long m = __ballot(cand);
    unsigned int wbase = 0;
    if ((tid & 63) == 0 && m) wbase = atomicAdd(gcnt, (unsigned int)__popcll(m));
    wbase = __shfl(wbase, 0, 64);
    if (cand) {
        unsigned int pos = wbase +
            (unsigned int)__popcll(m & ((1ULL << (tid & 63)) - 1ULL));
        keys[pos] = key;
    }
    if (tid == 0) { prefix_sh = 0ULL; r_sh = r0; }   // reset for phase 4
    __threadfence();
    cg::this_grid().sync();

    const unsigned int C = __hip_atomic_load(gcnt, __ATOMIC_RELAXED,
                                             __HIP_MEMORY_SCOPE_AGENT);

    // phase 4 (every block, redundant): radix select rank r0 over low-34 bits
    // of C candidate keys. Passes: 12 bits [33:22], 11 [21:11], 11 [10:0].
    hist[tid] = 0; hist[tid+1024] = 0; hist[tid+2048] = 0; hist[tid+3072] = 0;
    __syncthreads();
    for (int j = tid; j < (int)C; j += NT) {
        unsigned long long k34 = keys[j] & ((1ULL << 34) - 1ULL);
        atomicAdd(&hist[(unsigned int)(k34 >> 22)], 1u);
    }
    __syncthreads();
    scan_select<16, 12>(hist, partial, &prefix_sh, &r_sh);

    hist[tid] = 0; hist[tid+1024] = 0;
    __syncthreads();
    {
        const unsigned long long pref = prefix_sh;
        for (int j = tid; j < (int)C; j += NT) {
            unsigned long long k34 = keys[j] & ((1ULL << 34) - 1ULL);
            if ((k34 >> 22) == pref)
                atomicAdd(&hist[(unsigned int)(k34 >> 11) & 2047u], 1u);
        }
    }
    __syncthreads();
    scan_select<8, 11>(hist, partial, &prefix_sh, &r_sh);

    hist[tid] = 0; hist[tid+1024] = 0;
    __syncthreads();
    {
        const unsigned long long pref = prefix_sh;
        for (int j = tid; j < (int)C; j += NT) {
            unsigned long long k34 = keys[j] & ((1ULL << 34) - 1ULL);
            if ((k34 >> 11) == pref)
                atomicAdd(&hist[(unsigned int)k34 & 2047u], 1u);
        }
    }
    __syncthreads();
    scan_select<8, 11>(hist, partial, &prefix_sh, &r_sh);

    const unsigned long long T = ((unsigned long long)b0 << 34) | prefix_sh;

    // output 0: new_x (x, s, key all still in registers)
    out[i] = (key <= T) ? __fmul_rn(xi, __fadd_rn(s, 1.0f)) : 0.f;
}

extern "C" void kernel_launch(void* const* d_in, const int* in_sizes, int n_in,
                              void* d_out, int out_size, void* d_ws, size_t ws_size,
                              hipStream_t stream) {
    const float* x = (const float*)d_in[0];
    const float* w = (const float*)d_in[1];
    float* out = (float*)d_out;   // [0:N) new_x, [N:2N) attention_score
    unsigned int* ws = (unsigned int*)d_ws;
    void* args[] = { (void*)&x, (void*)&w, (void*)&out, (void*)&ws };
    hipLaunchCooperativeKernel((void*)fused_kernel, dim3(G), dim3(NT),
                               args, 0, stream);
}

// Round 5
// 87.712 us; speedup vs baseline: 1.1985x; 1.1985x over previous
//
#include <hip/hip_runtime.h>
#include <math.h>

#define N 16384
#define LIMIT 8192
#define NT 1024
#define G 16
#define FLAG_DONE 0x13572468u   // never equals 0xAAAAAAAA ws-poison

// key = (float_bits(score) << 14) | index  -- 44-bit unique sort key.
// score = sigmoid(y) in (0,1] => positive float, bits <= 0x3F800000 < 2^30,
// monotone; index < 2^14. (score,index) lex order == jnp stable argsort.
// T = rank-(LIMIT-1) key via distributed radix select; keep iff key <= T.
//
// 16 blocks x 1024 threads, REGULAR launch. Grid-wide sync via manual flag
// barriers in d_ws (device-scope atomics + agent fences). All 16 blocks are
// co-resident by construction (16 blocks, 1 block/CU min occupancy, 256 CUs),
// so spinning cannot deadlock.
//
// d_ws layout (uint32 units; poisoned 0xAA each iter, everything is
// written-before-read within one launch):
//   ws[0]          : gcnt   (candidate ticket counter; zeroed by blk 0)
//   ws[16..32)     : barA   (per-block flags, written once = FLAG_DONE)
//   ws[32..48)     : barB
//   ws[256..)      : keys[16384] (ull, 128KB)  -- compacted candidates
//   ws[256+32768..): ghist[G][1024]            -- per-block pass-0 hists

template <int W, int WIDTH>
__device__ __forceinline__ void scan_select(unsigned int* tot,
                                            unsigned int* partial,
                                            unsigned long long* prefix_sh,
                                            unsigned int* r_sh) {
    const int tid = threadIdx.x;
    const unsigned int r = *r_sh;          // written before preceding barrier
    if (tid < 256) {
        unsigned int p = 0;
#pragma unroll
        for (int q = 0; q < W / 4; ++q) {
            uint4 v = ((const uint4*)tot)[tid * (W / 4) + q];
            p += v.x + v.y + v.z + v.w;
        }
        partial[tid] = p;
    }
    __syncthreads();
    if (tid < 64) {                        // wave 0: wave-synchronous
        unsigned int p0 = partial[4*tid+0], p1 = partial[4*tid+1],
                     p2 = partial[4*tid+2], p3 = partial[4*tid+3];
        const unsigned int g4 = p0 + p1 + p2 + p3;
        unsigned int incl = g4;
#pragma unroll
        for (int d = 1; d < 64; d <<= 1) {
            unsigned int up = __shfl_up(incl, d, 64);
            if (tid >= d) incl += up;
        }
        unsigned long long ball = __ballot(incl > r);   // nonzero by rank invariant
        int L = __ffsll((long long)ball) - 1;
        if (tid == L) {
            unsigned int cum = incl - g4;
            unsigned int pp[4] = {p0, p1, p2, p3};
            int grp = -1;
#pragma unroll
            for (int k = 0; k < 4; ++k)
                if (grp < 0) { if (cum + pp[k] > r) grp = 4*L + k; else cum += pp[k]; }
            unsigned int c[W];
#pragma unroll
            for (int q = 0; q < W / 4; ++q) {           // batched, constant-indexed
                uint4 v = ((const uint4*)tot)[grp * (W / 4) + q];
                c[4*q+0] = v.x; c[4*q+1] = v.y; c[4*q+2] = v.z; c[4*q+3] = v.w;
            }
            int b = -1;
#pragma unroll
            for (int k = 0; k < W; ++k)
                if (b < 0) { if (cum + c[k] > r) b = grp * W + k; else cum += c[k]; }
            *r_sh = r - cum;
            *prefix_sh = (*prefix_sh << WIDTH) | (unsigned long long)b;
        }
    }
    __syncthreads();
}

// Grid barrier: every prior write device-visible, then set my flag, spin on all.
__device__ __forceinline__ void grid_barrier(unsigned int* flags, int blk, int tid) {
    __threadfence();                       // agent release: flush my block's writes
    __syncthreads();                       // whole block done + fenced
    if (tid == 0)
        __hip_atomic_store(&flags[blk], FLAG_DONE,
                           __ATOMIC_RELEASE, __HIP_MEMORY_SCOPE_AGENT);
    if (tid < G) {
        while (__hip_atomic_load(&flags[tid], __ATOMIC_ACQUIRE,
                                 __HIP_MEMORY_SCOPE_AGENT) != FLAG_DONE) { }
    }
    __syncthreads();
    __threadfence();                       // agent acquire: drop stale lines
}

__global__ __launch_bounds__(NT)
void fused_kernel(const float* __restrict__ x, const float* __restrict__ w,
                  float* __restrict__ out, unsigned int* __restrict__ ws) {
    __shared__ __attribute__((aligned(16))) float lds_x[NT + 6];
    __shared__ __attribute__((aligned(16))) unsigned int hist[4096];
    __shared__ __attribute__((aligned(16))) unsigned int partial[256];
    __shared__ unsigned long long prefix_sh;
    __shared__ unsigned int r_sh;

    const int tid = threadIdx.x;
    const int blk = blockIdx.x;
    const int base = blk * NT;
    const int i = base + tid;

    unsigned int* gcnt = ws;
    unsigned int* barA = ws + 16;
    unsigned int* barB = ws + 32;
    unsigned long long* keys = (unsigned long long*)(ws + 256);
    unsigned int* ghist = ws + 256 + 2 * 16384;

    if (blk == 0 && tid == 0)              // ordered before barrier-A release
        __hip_atomic_store(gcnt, 0u, __ATOMIC_RELAXED, __HIP_MEMORY_SCOPE_AGENT);

    float wv[7];
#pragma unroll
    for (int t = 0; t < 7; ++t) wv[t] = w[t];

    lds_x[3 + tid] = x[i];
    if (tid < 3) {
        int jl = base - 3 + tid;
        lds_x[tid] = (jl >= 0) ? x[jl] : 0.f;
        int jr = base + NT + tid;
        lds_x[NT + 3 + tid] = (jr < N) ? x[jr] : 0.f;
    }
    hist[tid] = 0u;                        // 1024-bin pass-0 histogram
    if (tid == 0) { prefix_sh = 0ULL; r_sh = LIMIT - 1; }
    __syncthreads();

    // conv + sigmoid: bit-exact vs numpy (sequential non-contracted mul/add, expf)
    float acc = 0.f;
#pragma unroll
    for (int t = 0; t < 7; ++t)
        acc = __fadd_rn(acc, __fmul_rn(lds_x[tid + t], wv[t]));
    const float s = 1.f / (1.f + expf(-acc));
    const float xi = lds_x[3 + tid];
    out[N + i] = s;                        // output 1: attention_score

    const unsigned long long key =
        ((unsigned long long)__float_as_uint(s) << 14) | (unsigned int)i;

    // phase 1: private histogram of key bits [43:34], dump to global
    atomicAdd(&hist[(unsigned int)(key >> 34)], 1u);
    __syncthreads();
    ghist[blk * NT + tid] = hist[tid];

    grid_barrier(barA, blk, tid);

    // phase 2 (redundant in every block): reduce G hists, find (b0, r0)
    unsigned int tsum = 0;
#pragma unroll
    for (int b = 0; b < G; ++b) tsum += ghist[b * NT + tid];   // coalesced
    hist[tid] = tsum;
    __syncthreads();
    scan_select<4, 10>(hist, partial, &prefix_sh, &r_sh);
    const unsigned int b0 = (unsigned int)prefix_sh;
    const unsigned int r0 = r_sh;
    __syncthreads();                       // all threads captured b0/r0 (fix r4 race)
    if (tid == 0) { prefix_sh = 0ULL; r_sh = r0; }   // reset for phase 4

    // phase 3: compact candidates (bucket == b0), wave-aggregated device ticket
    const bool cand = ((unsigned int)(key >> 34) == b0);
    const unsigned long long m = __ballot(cand);
    unsigned int wbase = 0;
    if ((tid & 63) == 0 && m) wbase = atomicAdd(gcnt, (unsigned int)__popcll(m));
    wbase = __shfl(wbase, 0, 64);
    if (cand) {
        unsigned int pos = wbase +
            (unsigned int)__popcll(m & ((1ULL << (tid & 63)) - 1ULL));
        keys[pos] = key;
    }

    grid_barrier(barB, blk, tid);

    const unsigned int C = __hip_atomic_load(gcnt, __ATOMIC_RELAXED,
                                             __HIP_MEMORY_SCOPE_AGENT);

    // phase 4 (redundant in every block): select rank r0 over low-34 bits of
    // the C candidates. Passes: 12 bits [33:22], 11 [21:11], 11 [10:0].
    hist[tid] = 0; hist[tid+1024] = 0; hist[tid+2048] = 0; hist[tid+3072] = 0;
    __syncthreads();
    for (int j = tid; j < (int)C; j += NT) {
        unsigned long long k34 = keys[j] & ((1ULL << 34) - 1ULL);
        atomicAdd(&hist[(unsigned int)(k34 >> 22)], 1u);
    }
    __syncthreads();
    scan_select<16, 12>(hist, partial, &prefix_sh, &r_sh);

    hist[tid] = 0; hist[tid+1024] = 0;
    __syncthreads();
    {
        const unsigned long long pref = prefix_sh;
        for (int j = tid; j < (int)C; j += NT) {
            unsigned long long k34 = keys[j] & ((1ULL << 34) - 1ULL);
            if ((k34 >> 22) == pref)
                atomicAdd(&hist[(unsigned int)(k34 >> 11) & 2047u], 1u);
        }
    }
    __syncthreads();
    scan_select<8, 11>(hist, partial, &prefix_sh, &r_sh);

    hist[tid] = 0; hist[tid+1024] = 0;
    __syncthreads();
    {
        const unsigned long long pref = prefix_sh;
        for (int j = tid; j < (int)C; j += NT) {
            unsigned long long k34 = keys[j] & ((1ULL << 34) - 1ULL);
            if ((k34 >> 11) == pref)
                atomicAdd(&hist[(unsigned int)k34 & 2047u], 1u);
        }
    }
    __syncthreads();
    scan_select<8, 11>(hist, partial, &prefix_sh, &r_sh);

    const unsigned long long T = ((unsigned long long)b0 << 34) | prefix_sh;

    // output 0: new_x (x, s, key all still in registers)
    out[i] = (key <= T) ? __fmul_rn(xi, __fadd_rn(s, 1.0f)) : 0.f;
}

extern "C" void kernel_launch(void* const* d_in, const int* in_sizes, int n_in,
                              void* d_out, int out_size, void* d_ws, size_t ws_size,
                              hipStream_t stream) {
    const float* x = (const float*)d_in[0];
    const float* w = (const float*)d_in[1];
    float* out = (float*)d_out;   // [0:N) new_x, [N:2N) attention_score
    unsigned int* ws = (unsigned int*)d_ws;
    fused_kernel<<<G, NT, 0, stream>>>(x, w, out, ws);
}

// Round 6
// 65.226 us; speedup vs baseline: 1.6117x; 1.3447x over previous
//
#include <hip/hip_runtime.h>
#include <math.h>

#define N 16384
#define LIMIT 8192

// key = (float_bits(score) << 14) | index  -- 44-bit unique sort key.
// score = sigmoid(y) in (0,1] => positive float, bits <= 0x3F800000 < 2^30,
// monotone; index < 2^14. (score,index) lex order == jnp stable argsort.
// T = rank-(LIMIT-1) key via radix select (10 + 12 + 11 + 11 bits); keep iff
// key <= T. Three regular kernels; kernel boundaries provide grid sync
// (no fences/spins -- r5 showed agent fences cost ~18us after the harness's
// 256MB L2-dirtying ws poison fill).
//
// ws layout (uint32 units; poisoned 0xAA, everything written before read):
//   ws[8..10)  : T (unsigned long long)
//   ws[256..)  : ghist[16][1024] -- per-block pass-0 histograms

template <int W, int WIDTH>
__device__ __forceinline__ void scan_select(unsigned int* tot,
                                            unsigned int* partial,
                                            unsigned long long* prefix_sh,
                                            unsigned int* r_sh) {
    const int tid = threadIdx.x;
    const unsigned int r = *r_sh;          // valid: written before prior barrier
    if (tid < 256) {
        unsigned int p = 0;
#pragma unroll
        for (int q = 0; q < W / 4; ++q) {
            uint4 v = ((const uint4*)tot)[tid * (W / 4) + q];
            p += v.x + v.y + v.z + v.w;
        }
        partial[tid] = p;
    }
    __syncthreads();
    if (tid < 64) {                        // wave 0: wave-synchronous
        unsigned int p0 = partial[4*tid+0], p1 = partial[4*tid+1],
                     p2 = partial[4*tid+2], p3 = partial[4*tid+3];
        const unsigned int g4 = p0 + p1 + p2 + p3;
        unsigned int incl = g4;
#pragma unroll
        for (int d = 1; d < 64; d <<= 1) {
            unsigned int up = __shfl_up(incl, d, 64);
            if (tid >= d) incl += up;
        }
        unsigned long long ball = __ballot(incl > r);   // nonzero by rank invariant
        int L = __ffsll((long long)ball) - 1;
        if (tid == L) {
            unsigned int cum = incl - g4;
            unsigned int pp[4] = {p0, p1, p2, p3};
            int grp = -1;
#pragma unroll
            for (int k = 0; k < 4; ++k)
                if (grp < 0) { if (cum + pp[k] > r) grp = 4*L + k; else cum += pp[k]; }
            unsigned int c[W];
#pragma unroll
            for (int q = 0; q < W / 4; ++q) {           // batched, constant-indexed
                uint4 v = ((const uint4*)tot)[grp * (W / 4) + q];
                c[4*q+0] = v.x; c[4*q+1] = v.y; c[4*q+2] = v.z; c[4*q+3] = v.w;
            }
            int b = -1;
#pragma unroll
            for (int k = 0; k < W; ++k)
                if (b < 0) { if (cum + c[k] > r) b = grp * W + k; else cum += c[k]; }
            *r_sh = r - cum;
            *prefix_sh = (*prefix_sh << WIDTH) | (unsigned long long)b;
        }
    }
    __syncthreads();
}

// K1: conv + sigmoid -> score; per-block 1024-bin histogram of key bits
// [43:34] (== float bits >> 20), 4-way spread -> ghist.
__global__ __launch_bounds__(1024)
void k1_score_hist(const float* __restrict__ x, const float* __restrict__ w,
                   float* __restrict__ out, unsigned int* __restrict__ ws) {
    __shared__ __attribute__((aligned(16))) float lds_x[1024 + 6];
    __shared__ __attribute__((aligned(16))) unsigned int h4[4096];
    const int tid = threadIdx.x;
    const int blk = blockIdx.x;
    const int base = blk * 1024;
    const int i = base + tid;

    float wv[7];
#pragma unroll
    for (int t = 0; t < 7; ++t) wv[t] = w[t];

    lds_x[3 + tid] = x[i];
    if (tid < 3) {
        int jl = base - 3 + tid;
        lds_x[tid] = (jl >= 0) ? x[jl] : 0.f;
        int jr = base + 1024 + tid;
        lds_x[1024 + 3 + tid] = (jr < N) ? x[jr] : 0.f;
    }
    h4[tid] = 0; h4[tid+1024] = 0; h4[tid+2048] = 0; h4[tid+3072] = 0;
    __syncthreads();

    // bit-exact vs numpy: sequential non-contracted mul/add, expf sigmoid
    float acc = 0.f;
#pragma unroll
    for (int t = 0; t < 7; ++t)
        acc = __fadd_rn(acc, __fmul_rn(lds_x[tid + t], wv[t]));
    const float s = 1.f / (1.f + expf(-acc));
    out[N + i] = s;                               // output 1: attention_score

    const unsigned int bin = __float_as_uint(s) >> 20;   // key>>34, < 1024
    atomicAdd(&h4[(bin << 2) | (tid & 3)], 1u);
    __syncthreads();
    ws[256 + blk * 1024 + tid] =
        h4[4*tid] + h4[4*tid+1] + h4[4*tid+2] + h4[4*tid+3];
}

// K2: single block. Reduce 16 histograms -> (b0, r0); then 3 predicate radix
// passes over all N keys (scores held in registers) -> T.
__global__ __launch_bounds__(1024)
void k2_select(const float* __restrict__ out, unsigned int* __restrict__ ws) {
    __shared__ __attribute__((aligned(16))) unsigned int hist[4096];
    __shared__ __attribute__((aligned(16))) unsigned int partial[256];
    __shared__ unsigned long long prefix_sh;
    __shared__ unsigned int r_sh;
    const int tid = threadIdx.x;
    const unsigned int* ghist = ws + 256;

    // 16 scores/thread into registers (contiguous chunk, float4 loads)
    float s[16];
    const float4* sv = (const float4*)(out + N) + tid * 4;
#pragma unroll
    for (int q = 0; q < 4; ++q) {
        float4 v = sv[q];
        s[4*q+0] = v.x; s[4*q+1] = v.y; s[4*q+2] = v.z; s[4*q+3] = v.w;
    }

    // pass 0 totals from ghist (coalesced)
    unsigned int tsum = 0;
#pragma unroll
    for (int b = 0; b < 16; ++b) tsum += ghist[b * 1024 + tid];
    hist[tid] = tsum;
    if (tid == 0) { prefix_sh = 0ULL; r_sh = LIMIT - 1; }
    __syncthreads();
    scan_select<4, 10>(hist, partial, &prefix_sh, &r_sh);   // prefix = b0

    const int base = tid * 16;
    // passes 1..3: widths 12,11,11; shifts 22,11,0; prefix accumulates, so
    // the predicate is always (key >> (shift+width)) == prefix.
    const int widths[3] = {12, 11, 11};
    const int shifts[3] = {22, 11, 0};
#pragma unroll
    for (int p = 0; p < 3; ++p) {
        const int width = widths[p], shift = shifts[p];
        const int B = 1 << width;
        hist[tid] = 0; hist[tid + 1024] = 0;
        if (width == 12) { hist[tid + 2048] = 0; hist[tid + 3072] = 0; }
        __syncthreads();
        const unsigned long long pref = prefix_sh;
#pragma unroll
        for (int k = 0; k < 16; ++k) {
            unsigned long long key = ((unsigned long long)__float_as_uint(s[k]) << 14)
                                     | (unsigned int)(base + k);
            if ((key >> (shift + width)) == pref)
                atomicAdd(&hist[(unsigned int)(key >> shift) & (unsigned int)(B - 1)], 1u);
        }
        __syncthreads();
        if (width == 12) scan_select<16, 12>(hist, partial, &prefix_sh, &r_sh);
        else             scan_select<8, 11>(hist, partial, &prefix_sh, &r_sh);
    }
    if (tid == 0) *(unsigned long long*)(ws + 8) = prefix_sh;   // T (44 bits)
}

// K3: parallel epilogue. new_x[i] = key<=T ? x*(s+1) : 0.
__global__ __launch_bounds__(256)
void k3_output(const float* __restrict__ x, float* __restrict__ out,
               const unsigned int* __restrict__ ws) {
    const int t = blockIdx.x * 256 + threadIdx.x;      // one float4 per thread
    const unsigned long long T = *(const unsigned long long*)(ws + 8);
    const float4 xv = ((const float4*)x)[t];
    const float4 sv = ((const float4*)(out + N))[t];
    const int base = t * 4;
    float4 o;
    const float* xp = &xv.x; const float* sp = &sv.x; float* op = &o.x;
#pragma unroll
    for (int e = 0; e < 4; ++e) {
        unsigned long long key = ((unsigned long long)__float_as_uint(sp[e]) << 14)
                                 | (unsigned int)(base + e);
        op[e] = (key <= T) ? __fmul_rn(xp[e], __fadd_rn(sp[e], 1.0f)) : 0.f;
    }
    ((float4*)out)[t] = o;
}

extern "C" void kernel_launch(void* const* d_in, const int* in_sizes, int n_in,
                              void* d_out, int out_size, void* d_ws, size_t ws_size,
                              hipStream_t stream) {
    const float* x = (const float*)d_in[0];
    const float* w = (const float*)d_in[1];
    float* out = (float*)d_out;   // [0:N) new_x, [N:2N) attention_score
    unsigned int* ws = (unsigned int*)d_ws;
    k1_score_hist<<<16, 1024, 0, stream>>>(x, w, out, ws);
    k2_select<<<1, 1024, 0, stream>>>(out, ws);
    k3_output<<<N / 1024, 256, 0, stream>>>(x, out, ws);
}